// Round 1
// baseline (88.439 us; speedup 1.0000x reference)
//
#include <hip/hip_runtime.h>

#define NROWS 8192
#define INCH 10
#define NQKV 33
#define OUTCH 11
#define KB 512  // K/V tile rows staged in LDS

// ---------------------------------------------------------------------------
// Kernel A: LayerNorm + Linear(10 -> 33) -> q*scale, k, v written to workspace
// as float4 "planes": ws[(part*3 + c)*NROWS + row] holds floats 4c..4c+3 of the
// (12-float-padded) row. part: 0=q, 1=k, 2=v. Pad elements written as 0.
// ---------------------------------------------------------------------------
__global__ __launch_bounds__(256) void qkv_ln_kernel(
    const float* __restrict__ x, const float* __restrict__ gamma,
    const float* __restrict__ beta, const float* __restrict__ W,
    float4* __restrict__ ws) {
  __shared__ float sW[NQKV * INCH];
  __shared__ float sg[INCH];
  __shared__ float sb[INCH];
  int tid = threadIdx.x;
  for (int i = tid; i < NQKV * INCH; i += 256) sW[i] = W[i];
  if (tid < INCH) { sg[tid] = gamma[tid]; sb[tid] = beta[tid]; }
  __syncthreads();

  int row = blockIdx.x * 256 + tid;  // grid sized exactly: row < NROWS
  float xv[INCH];
#pragma unroll
  for (int i = 0; i < INCH; ++i) xv[i] = x[row * INCH + i];

  float mu = 0.f;
#pragma unroll
  for (int i = 0; i < INCH; ++i) mu += xv[i];
  mu *= (1.0f / INCH);
  float var = 0.f;
#pragma unroll
  for (int i = 0; i < INCH; ++i) { float d = xv[i] - mu; var += d * d; }
  var *= (1.0f / INCH);
  float rstd = rsqrtf(var + 1e-5f);
  float h[INCH];
#pragma unroll
  for (int i = 0; i < INCH; ++i) h[i] = (xv[i] - mu) * rstd * sg[i] + sb[i];

  float acc[NQKV];
#pragma unroll
  for (int oc = 0; oc < NQKV; ++oc) {
    float s = 0.f;
#pragma unroll
    for (int i = 0; i < INCH; ++i) s += h[i] * sW[oc * INCH + i];
    acc[oc] = s;
  }
  const float qscale = 0.31622776601683794f;  // IN_CH^-0.5
#pragma unroll
  for (int oc = 0; oc < OUTCH; ++oc) acc[oc] *= qscale;

#pragma unroll
  for (int p = 0; p < 3; ++p) {
#pragma unroll
    for (int c = 0; c < 3; ++c) {
      float4 v;
      const int d0 = 4 * c;
      v.x = (d0 + 0 < OUTCH) ? acc[p * OUTCH + d0 + 0] : 0.f;
      v.y = (d0 + 1 < OUTCH) ? acc[p * OUTCH + d0 + 1] : 0.f;
      v.z = (d0 + 2 < OUTCH) ? acc[p * OUTCH + d0 + 2] : 0.f;
      v.w = (d0 + 3 < OUTCH) ? acc[p * OUTCH + d0 + 3] : 0.f;
      ws[(p * 3 + c) * NROWS + row] = v;
    }
  }
}

// ---------------------------------------------------------------------------
// Kernel B: streaming softmax attention. No row-max needed: |s| <= ~14 (bound
// via spectral norms of W_q, W_k and ||h||^2 = 10), exp() and the row-sum are
// comfortably inside fp32 range, and softmax is shift-invariant.
// Block = 256 thr = 4 waves; each wave owns 4 q rows (wave-uniform in VGPRs);
// lane = k-slot. K/V tiles (KB rows) staged in LDS as float4 planes; lane
// reads sK[it*64+lane] -> contiguous float4 across the wave (conflict-free).
// ---------------------------------------------------------------------------
__global__ __launch_bounds__(256, 2) void attn_kernel(
    const float4* __restrict__ ws, float* __restrict__ out) {
  __shared__ float4 sK[3 * KB];  // 24 KB
  __shared__ float4 sV[3 * KB];  // 24 KB
  int tid = threadIdx.x;
  int lane = tid & 63;
  int wv = tid >> 6;
  int row0 = blockIdx.x * 16 + wv * 4;  // 4 q-rows per wave

  const float4* Q = ws;
  const float4* K = ws + 3 * NROWS;
  const float4* V = ws + 6 * NROWS;

  float q[4][12];
#pragma unroll
  for (int u = 0; u < 4; ++u) {
#pragma unroll
    for (int c = 0; c < 3; ++c) {
      float4 t = Q[c * NROWS + row0 + u];
      q[u][4 * c + 0] = t.x;
      q[u][4 * c + 1] = t.y;
      q[u][4 * c + 2] = t.z;
      q[u][4 * c + 3] = t.w;
    }
  }

  float l[4] = {0.f, 0.f, 0.f, 0.f};
  float o[4][OUTCH];
#pragma unroll
  for (int u = 0; u < 4; ++u)
#pragma unroll
    for (int d = 0; d < OUTCH; ++d) o[u][d] = 0.f;

  for (int tile = 0; tile < NROWS / KB; ++tile) {
    const int jb = tile * KB;
    __syncthreads();
#pragma unroll
    for (int i = 0; i < (3 * KB) / 256; ++i) {
      int f = tid + 256 * i;      // [0, 3*KB)
      int c = f >> 9;             // KB == 512
      int j = f & (KB - 1);
      sK[f] = K[c * NROWS + jb + j];
      sV[f] = V[c * NROWS + jb + j];
    }
    __syncthreads();

    for (int it = 0; it < KB / 64; ++it) {
      int j = it * 64 + lane;
      float4 ka = sK[j], kb = sK[KB + j], kc = sK[2 * KB + j];
      float4 va = sV[j], vb = sV[KB + j], vc = sV[2 * KB + j];
      float kk[12] = {ka.x, ka.y, ka.z, ka.w, kb.x, kb.y,
                      kb.z, kb.w, kc.x, kc.y, kc.z, kc.w};
      float vv[12] = {va.x, va.y, va.z, va.w, vb.x, vb.y,
                      vb.z, vb.w, vc.x, vc.y, vc.z, vc.w};
#pragma unroll
      for (int u = 0; u < 4; ++u) {
        float s = 0.f;
#pragma unroll
        for (int d = 0; d < OUTCH; ++d) s += q[u][d] * kk[d];
        float p = __expf(s);
        l[u] += p;
#pragma unroll
        for (int d = 0; d < OUTCH; ++d) o[u][d] += p * vv[d];
      }
    }
  }

  // Butterfly sum across the 64 lanes (each lane covered a disjoint k subset).
#pragma unroll
  for (int m = 1; m < 64; m <<= 1) {
#pragma unroll
    for (int u = 0; u < 4; ++u) {
      l[u] += __shfl_xor(l[u], m, 64);
#pragma unroll
      for (int d = 0; d < OUTCH; ++d) o[u][d] += __shfl_xor(o[u][d], m, 64);
    }
  }

  if (lane == 0) {
#pragma unroll
    for (int u = 0; u < 4; ++u) {
      float inv = 1.0f / l[u];
#pragma unroll
      for (int d = 0; d < OUTCH; ++d)
        out[(size_t)(row0 + u) * OUTCH + d] = o[u][d] * inv;
    }
  }
}

extern "C" void kernel_launch(void* const* d_in, const int* in_sizes, int n_in,
                              void* d_out, int out_size, void* d_ws, size_t ws_size,
                              hipStream_t stream) {
  const float* x = (const float*)d_in[0];
  const float* gamma = (const float*)d_in[1];
  const float* beta = (const float*)d_in[2];
  const float* W = (const float*)d_in[3];
  float4* ws = (float4*)d_ws;   // needs 9*NROWS*16 B = 1.18 MB
  float* out = (float*)d_out;

  qkv_ln_kernel<<<NROWS / 256, 256, 0, stream>>>(x, gamma, beta, W, ws);
  attn_kernel<<<NROWS / 16, 256, 0, stream>>>(ws, out);
}